// Round 7
// baseline (200.849 us; speedup 1.0000x reference)
//
#include <hip/hip_runtime.h>

#define B 32768
#define D 1024
#define SEL 512
#define E 6
#define K 3
#define SH 32
#define HID 128
#define NKT 16    // K tiles of 64 (K = D = 1024)

typedef __attribute__((ext_vector_type(8))) short bf16x8;
typedef __attribute__((ext_vector_type(4))) float f32x4;

__device__ __forceinline__ unsigned short f2bf(float f) {
  unsigned u = __float_as_uint(f);
  return (unsigned short)((u + 0x7fffu + ((u >> 16) & 1u)) >> 16);
}

__device__ __forceinline__ void gload_lds16(const void* g, void* l) {
  __builtin_amdgcn_global_load_lds(
      (const __attribute__((address_space(1))) void*)g,
      (__attribute__((address_space(3))) void*)l, 16, 0, 0);
}

// ---------------- K0: per-expert inverse selection map (+ cnt zeroing) -------
__global__ void k_sel(const float* __restrict__ ml, int* __restrict__ inv,
                      int* __restrict__ cnt) {
  __shared__ float row[D];
  const int e = blockIdx.x, t = threadIdx.x;
  if (t == 0) cnt[e] = 0;
  row[t] = ml[e * D + t];
  __syncthreads();
  const float v = row[t];
  int rank = 0;
  for (int i = 0; i < D; ++i) {
    float u = row[i];
    rank += (u > v) || (u == v && i < t);
  }
  inv[e * D + t] = (rank < SEL) ? rank : -1;
}

// ---------------- K0b: transpose Wg -> WgT[e][d] (one-time, 24 KB) ----------
__global__ void k_wgt(const float* __restrict__ Wg, float* __restrict__ WgT) {
  const int idx = blockIdx.x * 256 + threadIdx.x;   // grid 24 -> 6144
  const int e = idx >> 10, d = idx & 1023;
  WgT[e * D + d] = Wg[(size_t)d * E + e];
}

// ---------------- K1a: WoWsp = Wo@Wsp (64x32) + bfull ----------------
__global__ __launch_bounds__(256) void k_wowsp(
    const float* __restrict__ Wo, const float* __restrict__ Wsp,
    const float* __restrict__ bo, const float* __restrict__ bsp,
    float* __restrict__ WoWsp, float* __restrict__ bfull) {
  __shared__ float red[256];
  const int t = threadIdx.x;
  const int j = t & 31, chunk = t >> 5;
  const int blk = blockIdx.x;
  float p = 0.f;
  if (blk < 64) {
    const int i = blk;
    for (int c = chunk * 64; c < chunk * 64 + 64; ++c)
      p += Wo[i * 512 + c] * Wsp[c * SH + j];
    red[t] = p;
    __syncthreads();
    if (t < 32) {
      float s = 0.f;
      #pragma unroll
      for (int k = 0; k < 8; ++k) s += red[k * 32 + j];
      WoWsp[i * SH + j] = s;
    }
  } else {
    for (int c = chunk * 64; c < chunk * 64 + 64; ++c)
      p += bo[c] * Wsp[c * SH + j];
    red[t] = p;
    __syncthreads();
    if (t < 32) {
      float s = bsp[j];
      #pragma unroll
      for (int k = 0; k < 8; ++k) s += red[k * 32 + j];
      bfull[j] = s;
    }
  }
}

// ---------------- K1b: Wfull = Wv @ WoWsp (512x32) ----------------
__global__ __launch_bounds__(256) void k_wfull2(
    const float* __restrict__ Wv, const float* __restrict__ WoWsp,
    float* __restrict__ Wfull) {
  __shared__ float wsh[64 * SH];
  const int t = threadIdx.x;
  for (int idx = t; idx < 64 * SH; idx += 256) wsh[idx] = WoWsp[idx];
  __syncthreads();
  const int c = blockIdx.x * 8 + (t >> 5), j = t & 31;
  float p = 0.f;
  #pragma unroll 8
  for (int i = 0; i < 64; ++i) p += Wv[c * 64 + i] * wsh[i * SH + j];
  Wfull[c * SH + j] = p;
}

// ---------------- K2: W1comb[e][h][d] bf16 (scatter + folded sinfo) ----------
__global__ __launch_bounds__(256) void k_w1c(
    const float* __restrict__ W1, const float* __restrict__ b1,
    const int* __restrict__ inv, const float* __restrict__ Wfull,
    const float* __restrict__ bfull,
    unsigned short* __restrict__ W1eT, float* __restrict__ b1c) {
  __shared__ float w1b[SH];
  __shared__ float bf[SH];
  const int e = blockIdx.x >> 7, h = blockIdx.x & 127;
  const int t = threadIdx.x;
  const float* We = W1 + (size_t)e * (SEL + SH) * HID;
  if (t < SH) { w1b[t] = We[(size_t)(SEL + t) * HID + h]; bf[t] = bfull[t]; }
  __syncthreads();
  const int* iv = inv + e * D;
  unsigned short* dst = W1eT + ((size_t)e * HID + h) * D;
  #pragma unroll
  for (int it = 0; it < 4; ++it) {
    int d = t + it * 256;
    int s = iv[d];
    float v = (s >= 0) ? We[(size_t)s * HID + h] : 0.f;
    if (d >= 512) {
      const float* wf = Wfull + (size_t)(d - 512) * SH;
      float p = 0.f;
      #pragma unroll
      for (int j = 0; j < SH; ++j) p += wf[j] * w1b[j];
      v += p;
    }
    dst[d] = f2bf(v);
  }
  if (t == 0) {
    float p = b1[e * HID + h];
    for (int j = 0; j < SH; ++j) p += bf[j] * w1b[j];
    b1c[e * HID + h] = p;
  }
}

// ---------------- K3: gate logits (fp32) + optional bf16 x conversion -------
// grid 1024 -> 4096 waves, 8 tokens/wave; coalesced WgT preload (96 VGPR);
// next-token loads double-buffered under current token's FMA/shfl.
template<bool WRITE_XBF>
__global__ __launch_bounds__(256) void k_xbf_gate(
    const float* __restrict__ x, const float* __restrict__ WgT,
    const float* __restrict__ bg, unsigned short* __restrict__ xbf,
    float* __restrict__ gl) {
  const int w = threadIdx.x >> 6, lane = threadIdx.x & 63;
  const int wid = blockIdx.x * 4 + w;
  float wg[E][4][4];
  #pragma unroll
  for (int e2 = 0; e2 < E; ++e2)
    #pragma unroll
    for (int i = 0; i < 4; ++i) {
      float4 v = *(const float4*)(WgT + e2 * D + i * 256 + lane * 4);
      wg[e2][i][0] = v.x; wg[e2][i][1] = v.y;
      wg[e2][i][2] = v.z; wg[e2][i][3] = v.w;
    }
  const int tok0 = wid * 8;
  float4 buf[4];
  #pragma unroll
  for (int i = 0; i < 4; ++i)
    buf[i] = *(const float4*)(x + (size_t)tok0 * D + i * 256 + lane * 4);
  for (int tt = 0; tt < 8; ++tt) {
    const int tok = tok0 + tt;
    float4 nxt[4];
    if (tt < 7) {
      #pragma unroll
      for (int i = 0; i < 4; ++i)
        nxt[i] = *(const float4*)(x + (size_t)(tok + 1) * D + i * 256 + lane * 4);
    }
    float acc[E] = {};
    #pragma unroll
    for (int i = 0; i < 4; ++i) {
      if (WRITE_XBF) {
        ushort4 h4;
        h4.x = f2bf(buf[i].x); h4.y = f2bf(buf[i].y);
        h4.z = f2bf(buf[i].z); h4.w = f2bf(buf[i].w);
        *(ushort4*)((char*)xbf + (size_t)tok * 2048 + i * 512 + lane * 8) = h4;
      }
      #pragma unroll
      for (int q = 0; q < 4; ++q) {
        float xv = (&buf[i].x)[q];
        #pragma unroll
        for (int e2 = 0; e2 < E; ++e2) acc[e2] += xv * wg[e2][i][q];
      }
    }
    #pragma unroll
    for (int e2 = 0; e2 < E; ++e2) {
      float s = acc[e2];
      s += __shfl_xor(s, 1); s += __shfl_xor(s, 2); s += __shfl_xor(s, 4);
      s += __shfl_xor(s, 8); s += __shfl_xor(s, 16); s += __shfl_xor(s, 32);
      acc[e2] = s;
    }
    if (lane == 0) {
      #pragma unroll
      for (int e2 = 0; e2 < E; ++e2) gl[(size_t)tok * E + e2] = acc[e2] + bg[e2];
    }
    if (tt < 7) {
      #pragma unroll
      for (int i = 0; i < 4; ++i) buf[i] = nxt[i];
    }
  }
}

// ---------------- K4: top-3 + softmax -> per-expert compacted lists ---------
__global__ __launch_bounds__(256) void k_topk(
    const float* __restrict__ gl, int* __restrict__ cnt,
    int* __restrict__ clist, float* __restrict__ wlist) {
  const int tok = blockIdx.x * 256 + threadIdx.x;
  const int lane = threadIdx.x & 63;
  float gv[E];
  #pragma unroll
  for (int e2 = 0; e2 < E; ++e2) gv[e2] = gl[(size_t)tok * E + e2];
  int idx[K]; float sc[K];
  bool used[E] = {};
  #pragma unroll
  for (int k = 0; k < K; ++k) {
    float best = -1e30f; int bi = 0;
    for (int e2 = 0; e2 < E; ++e2)
      if (!used[e2] && gv[e2] > best) { best = gv[e2]; bi = e2; }
    used[bi] = true; sc[k] = best; idx[k] = bi;
  }
  float s1 = __expf(sc[1] - sc[0]), s2 = __expf(sc[2] - sc[0]);
  float inv_s = 1.f / (1.f + s1 + s2);
  float tw[K] = {inv_s, s1 * inv_s, s2 * inv_s};
  const unsigned long long below = (1ULL << lane) - 1ULL;
  #pragma unroll
  for (int e2 = 0; e2 < E; ++e2) {
    int myk = -1;
    #pragma unroll
    for (int k = 0; k < K; ++k) if (idx[k] == e2) myk = k;
    unsigned long long m = __ballot(myk >= 0);
    if (m) {
      int tot = __popcll(m);
      int leader = __ffsll((long long)m) - 1;
      int base = 0;
      if (lane == leader) base = atomicAdd(&cnt[e2], tot);
      base = __shfl(base, leader);
      if (myk >= 0) {
        int pos = base + __popcll(m & below);
        clist[e2 * B + pos] = (tok << 2) | myk;
        wlist[e2 * B + pos] = tw[myk];
      }
    }
  }
}

// ---------------- K5: compacted per-expert GEMM + relu·W2 epilogue ----------
template<int AMODE>
__global__ __launch_bounds__(256) void k_gemm(
    const float* __restrict__ x, const unsigned short* __restrict__ xbf,
    const unsigned short* __restrict__ W1eT,
    const int* __restrict__ cnt, const int* __restrict__ clist,
    const float* __restrict__ wlist,
    const float* __restrict__ b1c, const float* __restrict__ W2,
    const float* __restrict__ b2, float* __restrict__ eo4) {
  __shared__ __align__(16) char ldsA[128 * 128];
  __shared__ __align__(16) char ldsB[128 * 128];
  __shared__ int tokl[128];
  __shared__ float red[128];

  const int t = threadIdx.x;
  const int e = blockIdx.x >> 8;     // grid = E * 256
  const int bm = blockIdx.x & 255;
  const int n = cnt[e];
  if (bm * 128 >= n) return;
  const int cb = e * B;

  if (t < 128) {
    int gr = bm * 128 + t;
    tokl[t] = clist[cb + (gr < n ? gr : 0)] >> 2;
  }
  __syncthreads();

  const int w = t >> 6, lane = t & 63;
  const int g = lane >> 4, j = lane & 15;
  const int swz = ((lane & 7) * 16) ^ ((lane >> 3) << 4);

  const char* srcB[4];
  #pragma unroll
  for (int q = 0; q < 4; ++q)
    srcB[q] = (const char*)W1eT +
              (size_t)(e * HID + w * 32 + q * 8 + (lane >> 3)) * (D * 2) + swz;
  const char* srcA[4];
  if (AMODE == 0) {
    #pragma unroll
    for (int q = 0; q < 4; ++q)
      srcA[q] = (const char*)xbf +
                (size_t)tokl[w * 32 + q * 8 + (lane >> 3)] * 2048 + swz;
  }

  f32x4 acc[2][8] = {};

  for (int kt = 0; kt < NKT; ++kt) {
    if (kt) __syncthreads();
    if (AMODE == 0) {
      #pragma unroll
      for (int q = 0; q < 4; ++q)
        gload_lds16(srcA[q] + kt * 128, ldsA + w * 4096 + q * 1024);
    }
    #pragma unroll
    for (int q = 0; q < 4; ++q)
      gload_lds16(srcB[q] + kt * 128, ldsB + w * 4096 + q * 1024);
    if (AMODE == 1) {
      #pragma unroll
      for (int it = 0; it < 8; ++it) {
        int r = (t >> 4) + it * 16;
        const float4 v =
            *(const float4*)(x + (size_t)tokl[r] * D + kt * 64 + (t & 15) * 4);
        ushort4 h4;
        h4.x = f2bf(v.x); h4.y = f2bf(v.y); h4.z = f2bf(v.z); h4.w = f2bf(v.w);
        *(ushort4*)(ldsA + r * 128 + (((t & 15) * 8) ^ ((r & 7) << 4))) = h4;
      }
    }
    __syncthreads();
    #pragma unroll
    for (int kk = 0; kk < 2; ++kk) {
      const int kb = kk * 64 + g * 16;
      bf16x8 aF[2];
      #pragma unroll
      for (int fm = 0; fm < 2; ++fm) {
        int row = w * 32 + fm * 16 + j;
        aF[fm] = *(const bf16x8*)(ldsA + row * 128 + (kb ^ ((row & 7) << 4)));
      }
      #pragma unroll
      for (int fn = 0; fn < 8; ++fn) {
        int col = fn * 16 + j;
        bf16x8 bF = *(const bf16x8*)(ldsB + col * 128 + (kb ^ ((col & 7) << 4)));
        acc[0][fn] = __builtin_amdgcn_mfma_f32_16x16x32_bf16(aF[0], bF, acc[0][fn], 0, 0, 0);
        acc[1][fn] = __builtin_amdgcn_mfma_f32_16x16x32_bf16(aF[1], bF, acc[1][fn], 0, 0, 0);
      }
    }
  }

  float vb1[8], vw2[8];
  #pragma unroll
  for (int fn = 0; fn < 8; ++fn) {
    int col = fn * 16 + j;
    vb1[fn] = b1c[e * HID + col];
    vw2[fn] = W2[e * HID + col];
  }
  #pragma unroll
  for (int fm = 0; fm < 2; ++fm) {
    #pragma unroll
    for (int r = 0; r < 4; ++r) {
      float s = 0.f;
      #pragma unroll
      for (int fn = 0; fn < 8; ++fn)
        s += fmaxf(acc[fm][fn][r] + vb1[fn], 0.f) * vw2[fn];
      s += __shfl_xor(s, 1); s += __shfl_xor(s, 2);
      s += __shfl_xor(s, 4); s += __shfl_xor(s, 8);
      if (j == 0) red[w * 32 + fm * 16 + g * 4 + r] = s;
    }
  }
  __syncthreads();
  if (t < 128) {
    int gr = bm * 128 + t;
    if (gr < n) {
      int en = clist[cb + gr];
      eo4[(size_t)(en >> 2) * 4 + (en & 3)] = wlist[cb + gr] * (red[t] + b2[e]);
    }
  }
}

// ---------------- K6: sum the 3 weighted slots ----------------
__global__ void k_comb2(const float* __restrict__ eo4, float* __restrict__ out) {
  const int tok = blockIdx.x * 256 + threadIdx.x;
  float4 v = *(const float4*)(eo4 + (size_t)tok * 4);
  out[tok] = v.x + v.y + v.z;
}

extern "C" void kernel_launch(void* const* d_in, const int* in_sizes, int n_in,
                              void* d_out, int out_size, void* d_ws, size_t ws_size,
                              hipStream_t stream) {
  const float* x   = (const float*)d_in[0];
  const float* Wv  = (const float*)d_in[3];
  const float* Wo  = (const float*)d_in[4];
  const float* bo  = (const float*)d_in[5];
  const float* Wsp = (const float*)d_in[6];
  const float* bsp = (const float*)d_in[7];
  const float* Wg  = (const float*)d_in[8];
  const float* bg  = (const float*)d_in[9];
  const float* ml  = (const float*)d_in[10];
  const float* W1  = (const float*)d_in[11];
  const float* b1  = (const float*)d_in[12];
  const float* W2  = (const float*)d_in[13];
  const float* b2  = (const float*)d_in[14];
  float* out = (float*)d_out;

  char* ws = (char*)d_ws;
  int*   inv   = (int*)ws;                        // 24 KB
  float* WoWsp = (float*)(ws + 24576);            // 8 KB
  float* Wfull = (float*)(ws + 32768);            // 64 KB
  float* bfull = (float*)(ws + 98304);            // 128 B
  float* b1c   = (float*)(ws + 102400);           // 3 KB
  int*   cnt   = (int*)(ws + 106496);             // 32 B
  float* WgT   = (float*)(ws + 110592);           // 24 KB
  float* gl    = (float*)(ws + 139264);           // 768 KB
  int*   clist = (int*)(ws + 925696);             // 768 KB
  float* wlist = (float*)(ws + 1712128);          // 768 KB
  float* eo4   = (float*)(ws + 2498560);          // 512 KB
  unsigned short* W1eT = (unsigned short*)(ws + 3022848);  // 1.5 MB
  unsigned short* xbf  = (unsigned short*)(ws + 4595712);  // 64 MB (optional)
  const bool use_xbf = ws_size >= (size_t)4595712 + (size_t)B * D * 2;

  k_sel<<<E, D, 0, stream>>>(ml, inv, cnt);
  k_wgt<<<24, 256, 0, stream>>>(Wg, WgT);
  k_wowsp<<<65, 256, 0, stream>>>(Wo, Wsp, bo, bsp, WoWsp, bfull);
  k_wfull2<<<64, 256, 0, stream>>>(Wv, WoWsp, Wfull);
  k_w1c<<<E * HID, 256, 0, stream>>>(W1, b1, inv, Wfull, bfull, W1eT, b1c);
  if (use_xbf)
    k_xbf_gate<true><<<B / 32, 256, 0, stream>>>(x, WgT, bg, xbf, gl);
  else
    k_xbf_gate<false><<<B / 32, 256, 0, stream>>>(x, WgT, bg, xbf, gl);
  k_topk<<<B / 256, 256, 0, stream>>>(gl, cnt, clist, wlist);
  if (use_xbf)
    k_gemm<0><<<E * 256, 256, 0, stream>>>(x, xbf, W1eT, cnt, clist, wlist, b1c, W2, b2, eo4);
  else
    k_gemm<1><<<E * 256, 256, 0, stream>>>(x, xbf, W1eT, cnt, clist, wlist, b1c, W2, b2, eo4);
  k_comb2<<<B / 256, 256, 0, stream>>>(eo4, out);
}

// Round 8
// 200.588 us; speedup vs baseline: 1.0013x; 1.0013x over previous
//
#include <hip/hip_runtime.h>

#define B 32768
#define D 1024
#define SEL 512
#define E 6
#define K 3
#define SH 32
#define HID 128
#define NKT 16    // K tiles of 64 (K = D = 1024)

typedef __attribute__((ext_vector_type(8))) short bf16x8;
typedef __attribute__((ext_vector_type(4))) float f32x4;

__device__ __forceinline__ unsigned short f2bf(float f) {
  unsigned u = __float_as_uint(f);
  return (unsigned short)((u + 0x7fffu + ((u >> 16) & 1u)) >> 16);
}

__device__ __forceinline__ void gload_lds16(const void* g, void* l) {
  __builtin_amdgcn_global_load_lds(
      (const __attribute__((address_space(1))) void*)g,
      (__attribute__((address_space(3))) void*)l, 16, 0, 0);
}

// ---------------- K0: per-expert inverse selection map (+ cnt zeroing) -------
__global__ void k_sel(const float* __restrict__ ml, int* __restrict__ inv,
                      int* __restrict__ cnt) {
  __shared__ float row[D];
  const int e = blockIdx.x, t = threadIdx.x;
  if (t == 0) cnt[e] = 0;
  row[t] = ml[e * D + t];
  __syncthreads();
  const float v = row[t];
  int rank = 0;
  for (int i = 0; i < D; ++i) {
    float u = row[i];
    rank += (u > v) || (u == v && i < t);
  }
  inv[e * D + t] = (rank < SEL) ? rank : -1;
}

// ---------------- K0b: transpose Wg -> WgT[e][d] (one-time, 24 KB) ----------
__global__ void k_wgt(const float* __restrict__ Wg, float* __restrict__ WgT) {
  const int idx = blockIdx.x * 256 + threadIdx.x;   // grid 24 -> 6144
  const int e = idx >> 10, d = idx & 1023;
  WgT[e * D + d] = Wg[(size_t)d * E + e];
}

// ---------------- K1a: WoWsp = Wo@Wsp (64x32) + bfull ----------------
__global__ __launch_bounds__(256) void k_wowsp(
    const float* __restrict__ Wo, const float* __restrict__ Wsp,
    const float* __restrict__ bo, const float* __restrict__ bsp,
    float* __restrict__ WoWsp, float* __restrict__ bfull) {
  __shared__ float red[256];
  const int t = threadIdx.x;
  const int j = t & 31, chunk = t >> 5;
  const int blk = blockIdx.x;
  float p = 0.f;
  if (blk < 64) {
    const int i = blk;
    for (int c = chunk * 64; c < chunk * 64 + 64; ++c)
      p += Wo[i * 512 + c] * Wsp[c * SH + j];
    red[t] = p;
    __syncthreads();
    if (t < 32) {
      float s = 0.f;
      #pragma unroll
      for (int k = 0; k < 8; ++k) s += red[k * 32 + j];
      WoWsp[i * SH + j] = s;
    }
  } else {
    for (int c = chunk * 64; c < chunk * 64 + 64; ++c)
      p += bo[c] * Wsp[c * SH + j];
    red[t] = p;
    __syncthreads();
    if (t < 32) {
      float s = bsp[j];
      #pragma unroll
      for (int k = 0; k < 8; ++k) s += red[k * 32 + j];
      bfull[j] = s;
    }
  }
}

// ---------------- K1b: Wfull = Wv @ WoWsp (512x32) ----------------
__global__ __launch_bounds__(256) void k_wfull2(
    const float* __restrict__ Wv, const float* __restrict__ WoWsp,
    float* __restrict__ Wfull) {
  __shared__ float wsh[64 * SH];
  const int t = threadIdx.x;
  for (int idx = t; idx < 64 * SH; idx += 256) wsh[idx] = WoWsp[idx];
  __syncthreads();
  const int c = blockIdx.x * 8 + (t >> 5), j = t & 31;
  float p = 0.f;
  #pragma unroll 8
  for (int i = 0; i < 64; ++i) p += Wv[c * 64 + i] * wsh[i * SH + j];
  Wfull[c * SH + j] = p;
}

// ---------------- K2: W1comb[e][h][d] bf16 (scatter + folded sinfo) ----------
__global__ __launch_bounds__(256) void k_w1c(
    const float* __restrict__ W1, const float* __restrict__ b1,
    const int* __restrict__ inv, const float* __restrict__ Wfull,
    const float* __restrict__ bfull,
    unsigned short* __restrict__ W1eT, float* __restrict__ b1c) {
  __shared__ float w1b[SH];
  __shared__ float bf[SH];
  const int e = blockIdx.x >> 7, h = blockIdx.x & 127;
  const int t = threadIdx.x;
  const float* We = W1 + (size_t)e * (SEL + SH) * HID;
  if (t < SH) { w1b[t] = We[(size_t)(SEL + t) * HID + h]; bf[t] = bfull[t]; }
  __syncthreads();
  const int* iv = inv + e * D;
  unsigned short* dst = W1eT + ((size_t)e * HID + h) * D;
  #pragma unroll
  for (int it = 0; it < 4; ++it) {
    int d = t + it * 256;
    int s = iv[d];
    float v = (s >= 0) ? We[(size_t)s * HID + h] : 0.f;
    if (d >= 512) {
      const float* wf = Wfull + (size_t)(d - 512) * SH;
      float p = 0.f;
      #pragma unroll
      for (int j = 0; j < SH; ++j) p += wf[j] * w1b[j];
      v += p;
    }
    dst[d] = f2bf(v);
  }
  if (t == 0) {
    float p = b1[e * HID + h];
    for (int j = 0; j < SH; ++j) p += bf[j] * w1b[j];
    b1c[e * HID + h] = p;
  }
}

// ---------------- K3: gate logits (fp32) + bf16 x conversion ----------------
// 8 tokens/wave; Wg in 24 f32x4 VGPRs (coalesced WgT loads); x double-buffered
// in NAMED registers; __launch_bounds__(256,2) prevents register demotion.
template<bool WRITE_XBF>
__global__ __launch_bounds__(256, 2) void k_xbf_gate(
    const float* __restrict__ x, const float* __restrict__ WgT,
    const float* __restrict__ bg, unsigned short* __restrict__ xbf,
    float* __restrict__ gl) {
  const int w = threadIdx.x >> 6, lane = threadIdx.x & 63;
  const int wid = blockIdx.x * 4 + w;   // grid B/32 -> 4096 waves
  const int tok0 = wid * 8;

  f32x4 wg[E][4];
  #pragma unroll
  for (int e2 = 0; e2 < E; ++e2)
    #pragma unroll
    for (int i = 0; i < 4; ++i)
      wg[e2][i] = *(const f32x4*)(WgT + e2 * D + i * 256 + lane * 4);
  float bgv[E];
  #pragma unroll
  for (int e2 = 0; e2 < E; ++e2) bgv[e2] = bg[e2];

#define LOADX(R0, R1, R2, R3, tk)                                        \
  {                                                                       \
    const f32x4* p_ = (const f32x4*)(x + (size_t)(tk) * D + lane * 4);    \
    R0 = p_[0]; R1 = p_[64]; R2 = p_[128]; R3 = p_[192];                  \
  }

#define DO_TOKEN(R0, R1, R2, R3, tk)                                      \
  {                                                                       \
    if (WRITE_XBF) {                                                      \
      ushort4 h4;                                                         \
      h4.x = f2bf(R0[0]); h4.y = f2bf(R0[1]);                             \
      h4.z = f2bf(R0[2]); h4.w = f2bf(R0[3]);                             \
      *(ushort4*)((char*)xbf + (size_t)(tk) * 2048 + 0 * 512 + lane * 8) = h4; \
      h4.x = f2bf(R1[0]); h4.y = f2bf(R1[1]);                             \
      h4.z = f2bf(R1[2]); h4.w = f2bf(R1[3]);                             \
      *(ushort4*)((char*)xbf + (size_t)(tk) * 2048 + 1 * 512 + lane * 8) = h4; \
      h4.x = f2bf(R2[0]); h4.y = f2bf(R2[1]);                             \
      h4.z = f2bf(R2[2]); h4.w = f2bf(R2[3]);                             \
      *(ushort4*)((char*)xbf + (size_t)(tk) * 2048 + 2 * 512 + lane * 8) = h4; \
      h4.x = f2bf(R3[0]); h4.y = f2bf(R3[1]);                             \
      h4.z = f2bf(R3[2]); h4.w = f2bf(R3[3]);                             \
      *(ushort4*)((char*)xbf + (size_t)(tk) * 2048 + 3 * 512 + lane * 8) = h4; \
    }                                                                     \
    float acc[E];                                                         \
    _Pragma("unroll")                                                     \
    for (int e2 = 0; e2 < E; ++e2) {                                      \
      f32x4 s4 = R0 * wg[e2][0] + R1 * wg[e2][1]                          \
               + R2 * wg[e2][2] + R3 * wg[e2][3];                         \
      acc[e2] = s4[0] + s4[1] + s4[2] + s4[3];                            \
    }                                                                     \
    _Pragma("unroll")                                                     \
    for (int e2 = 0; e2 < E; ++e2) {                                      \
      float s = acc[e2];                                                  \
      s += __shfl_xor(s, 1); s += __shfl_xor(s, 2); s += __shfl_xor(s, 4);\
      s += __shfl_xor(s, 8); s += __shfl_xor(s, 16); s += __shfl_xor(s, 32);\
      acc[e2] = s;                                                        \
    }                                                                     \
    if (lane == 0) {                                                      \
      _Pragma("unroll")                                                   \
      for (int e2 = 0; e2 < E; ++e2)                                      \
        gl[(size_t)(tk) * E + e2] = acc[e2] + bgv[e2];                    \
    }                                                                     \
  }

  f32x4 A0, A1, A2, A3, B0, B1, B2, B3;
  LOADX(A0, A1, A2, A3, tok0 + 0);
  LOADX(B0, B1, B2, B3, tok0 + 1);
  #pragma unroll
  for (int tt = 0; tt < 8; tt += 2) {
    DO_TOKEN(A0, A1, A2, A3, tok0 + tt);
    if (tt < 6) LOADX(A0, A1, A2, A3, tok0 + tt + 2);
    DO_TOKEN(B0, B1, B2, B3, tok0 + tt + 1);
    if (tt < 6) LOADX(B0, B1, B2, B3, tok0 + tt + 3);
  }
#undef LOADX
#undef DO_TOKEN
}

// ---------------- K4: top-3 + softmax -> per-expert compacted lists ---------
__global__ __launch_bounds__(256) void k_topk(
    const float* __restrict__ gl, int* __restrict__ cnt,
    int* __restrict__ clist, float* __restrict__ wlist) {
  const int tok = blockIdx.x * 256 + threadIdx.x;
  const int lane = threadIdx.x & 63;
  float gv[E];
  #pragma unroll
  for (int e2 = 0; e2 < E; ++e2) gv[e2] = gl[(size_t)tok * E + e2];
  int idx[K]; float sc[K];
  bool used[E] = {};
  #pragma unroll
  for (int k = 0; k < K; ++k) {
    float best = -1e30f; int bi = 0;
    for (int e2 = 0; e2 < E; ++e2)
      if (!used[e2] && gv[e2] > best) { best = gv[e2]; bi = e2; }
    used[bi] = true; sc[k] = best; idx[k] = bi;
  }
  float s1 = __expf(sc[1] - sc[0]), s2 = __expf(sc[2] - sc[0]);
  float inv_s = 1.f / (1.f + s1 + s2);
  float tw[K] = {inv_s, s1 * inv_s, s2 * inv_s};
  const unsigned long long below = (1ULL << lane) - 1ULL;
  #pragma unroll
  for (int e2 = 0; e2 < E; ++e2) {
    int myk = -1;
    #pragma unroll
    for (int k = 0; k < K; ++k) if (idx[k] == e2) myk = k;
    unsigned long long m = __ballot(myk >= 0);
    if (m) {
      int tot = __popcll(m);
      int leader = __ffsll((long long)m) - 1;
      int base = 0;
      if (lane == leader) base = atomicAdd(&cnt[e2], tot);
      base = __shfl(base, leader);
      if (myk >= 0) {
        int pos = base + __popcll(m & below);
        clist[e2 * B + pos] = (tok << 2) | myk;
        wlist[e2 * B + pos] = tw[myk];
      }
    }
  }
}

// ---------------- K5: compacted per-expert GEMM + relu·W2 epilogue ----------
template<int AMODE>
__global__ __launch_bounds__(256) void k_gemm(
    const float* __restrict__ x, const unsigned short* __restrict__ xbf,
    const unsigned short* __restrict__ W1eT,
    const int* __restrict__ cnt, const int* __restrict__ clist,
    const float* __restrict__ wlist,
    const float* __restrict__ b1c, const float* __restrict__ W2,
    const float* __restrict__ b2, float* __restrict__ eo4) {
  __shared__ __align__(16) char ldsA[128 * 128];
  __shared__ __align__(16) char ldsB[128 * 128];
  __shared__ int tokl[128];
  __shared__ float red[128];

  const int t = threadIdx.x;
  const int e = blockIdx.x >> 8;     // grid = E * 256
  const int bm = blockIdx.x & 255;
  const int n = cnt[e];
  if (bm * 128 >= n) return;
  const int cb = e * B;

  if (t < 128) {
    int gr = bm * 128 + t;
    tokl[t] = clist[cb + (gr < n ? gr : 0)] >> 2;
  }
  __syncthreads();

  const int w = t >> 6, lane = t & 63;
  const int g = lane >> 4, j = lane & 15;
  const int swz = ((lane & 7) * 16) ^ ((lane >> 3) << 4);

  const char* srcB[4];
  #pragma unroll
  for (int q = 0; q < 4; ++q)
    srcB[q] = (const char*)W1eT +
              (size_t)(e * HID + w * 32 + q * 8 + (lane >> 3)) * (D * 2) + swz;
  const char* srcA[4];
  if (AMODE == 0) {
    #pragma unroll
    for (int q = 0; q < 4; ++q)
      srcA[q] = (const char*)xbf +
                (size_t)tokl[w * 32 + q * 8 + (lane >> 3)] * 2048 + swz;
  }

  f32x4 acc[2][8] = {};

  for (int kt = 0; kt < NKT; ++kt) {
    if (kt) __syncthreads();
    if (AMODE == 0) {
      #pragma unroll
      for (int q = 0; q < 4; ++q)
        gload_lds16(srcA[q] + kt * 128, ldsA + w * 4096 + q * 1024);
    }
    #pragma unroll
    for (int q = 0; q < 4; ++q)
      gload_lds16(srcB[q] + kt * 128, ldsB + w * 4096 + q * 1024);
    if (AMODE == 1) {
      #pragma unroll
      for (int it = 0; it < 8; ++it) {
        int r = (t >> 4) + it * 16;
        const float4 v =
            *(const float4*)(x + (size_t)tokl[r] * D + kt * 64 + (t & 15) * 4);
        ushort4 h4;
        h4.x = f2bf(v.x); h4.y = f2bf(v.y); h4.z = f2bf(v.z); h4.w = f2bf(v.w);
        *(ushort4*)(ldsA + r * 128 + (((t & 15) * 8) ^ ((r & 7) << 4))) = h4;
      }
    }
    __syncthreads();
    #pragma unroll
    for (int kk = 0; kk < 2; ++kk) {
      const int kb = kk * 64 + g * 16;
      bf16x8 aF[2];
      #pragma unroll
      for (int fm = 0; fm < 2; ++fm) {
        int row = w * 32 + fm * 16 + j;
        aF[fm] = *(const bf16x8*)(ldsA + row * 128 + (kb ^ ((row & 7) << 4)));
      }
      #pragma unroll
      for (int fn = 0; fn < 8; ++fn) {
        int col = fn * 16 + j;
        bf16x8 bF = *(const bf16x8*)(ldsB + col * 128 + (kb ^ ((col & 7) << 4)));
        acc[0][fn] = __builtin_amdgcn_mfma_f32_16x16x32_bf16(aF[0], bF, acc[0][fn], 0, 0, 0);
        acc[1][fn] = __builtin_amdgcn_mfma_f32_16x16x32_bf16(aF[1], bF, acc[1][fn], 0, 0, 0);
      }
    }
  }

  float vb1[8], vw2[8];
  #pragma unroll
  for (int fn = 0; fn < 8; ++fn) {
    int col = fn * 16 + j;
    vb1[fn] = b1c[e * HID + col];
    vw2[fn] = W2[e * HID + col];
  }
  #pragma unroll
  for (int fm = 0; fm < 2; ++fm) {
    #pragma unroll
    for (int r = 0; r < 4; ++r) {
      float s = 0.f;
      #pragma unroll
      for (int fn = 0; fn < 8; ++fn)
        s += fmaxf(acc[fm][fn][r] + vb1[fn], 0.f) * vw2[fn];
      s += __shfl_xor(s, 1); s += __shfl_xor(s, 2);
      s += __shfl_xor(s, 4); s += __shfl_xor(s, 8);
      if (j == 0) red[w * 32 + fm * 16 + g * 4 + r] = s;
    }
  }
  __syncthreads();
  if (t < 128) {
    int gr = bm * 128 + t;
    if (gr < n) {
      int en = clist[cb + gr];
      eo4[(size_t)(en >> 2) * 4 + (en & 3)] = wlist[cb + gr] * (red[t] + b2[e]);
    }
  }
}

// ---------------- K6: sum the 3 weighted slots ----------------
__global__ void k_comb2(const float* __restrict__ eo4, float* __restrict__ out) {
  const int tok = blockIdx.x * 256 + threadIdx.x;
  float4 v = *(const float4*)(eo4 + (size_t)tok * 4);
  out[tok] = v.x + v.y + v.z;
}

extern "C" void kernel_launch(void* const* d_in, const int* in_sizes, int n_in,
                              void* d_out, int out_size, void* d_ws, size_t ws_size,
                              hipStream_t stream) {
  const float* x   = (const float*)d_in[0];
  const float* Wv  = (const float*)d_in[3];
  const float* Wo  = (const float*)d_in[4];
  const float* bo  = (const float*)d_in[5];
  const float* Wsp = (const float*)d_in[6];
  const float* bsp = (const float*)d_in[7];
  const float* Wg  = (const float*)d_in[8];
  const float* bg  = (const float*)d_in[9];
  const float* ml  = (const float*)d_in[10];
  const float* W1  = (const float*)d_in[11];
  const float* b1  = (const float*)d_in[12];
  const float* W2  = (const float*)d_in[13];
  const float* b2  = (const float*)d_in[14];
  float* out = (float*)d_out;

  char* ws = (char*)d_ws;
  int*   inv   = (int*)ws;                        // 24 KB
  float* WoWsp = (float*)(ws + 24576);            // 8 KB
  float* Wfull = (float*)(ws + 32768);            // 64 KB
  float* bfull = (float*)(ws + 98304);            // 128 B
  float* b1c   = (float*)(ws + 102400);           // 3 KB
  int*   cnt   = (int*)(ws + 106496);             // 32 B
  float* WgT   = (float*)(ws + 110592);           // 24 KB
  float* gl    = (float*)(ws + 139264);           // 768 KB
  int*   clist = (int*)(ws + 925696);             // 768 KB
  float* wlist = (float*)(ws + 1712128);          // 768 KB
  float* eo4   = (float*)(ws + 2498560);          // 512 KB
  unsigned short* W1eT = (unsigned short*)(ws + 3022848);  // 1.5 MB
  unsigned short* xbf  = (unsigned short*)(ws + 4595712);  // 64 MB (optional)
  const bool use_xbf = ws_size >= (size_t)4595712 + (size_t)B * D * 2;

  k_sel<<<E, D, 0, stream>>>(ml, inv, cnt);
  k_wgt<<<24, 256, 0, stream>>>(Wg, WgT);
  k_wowsp<<<65, 256, 0, stream>>>(Wo, Wsp, bo, bsp, WoWsp, bfull);
  k_wfull2<<<64, 256, 0, stream>>>(Wv, WoWsp, Wfull);
  k_w1c<<<E * HID, 256, 0, stream>>>(W1, b1, inv, Wfull, bfull, W1eT, b1c);
  if (use_xbf)
    k_xbf_gate<true><<<B / 32, 256, 0, stream>>>(x, WgT, bg, xbf, gl);
  else
    k_xbf_gate<false><<<B / 32, 256, 0, stream>>>(x, WgT, bg, xbf, gl);
  k_topk<<<B / 256, 256, 0, stream>>>(gl, cnt, clist, wlist);
  if (use_xbf)
    k_gemm<0><<<E * 256, 256, 0, stream>>>(x, xbf, W1eT, cnt, clist, wlist, b1c, W2, b2, eo4);
  else
    k_gemm<1><<<E * 256, 256, 0, stream>>>(x, xbf, W1eT, cnt, clist, wlist, b1c, W2, b2, eo4);
  k_comb2<<<B / 256, 256, 0, stream>>>(eo4, out);
}

// Round 9
// 189.906 us; speedup vs baseline: 1.0576x; 1.0563x over previous
//
#include <hip/hip_runtime.h>

#define B 32768
#define D 1024
#define SEL 512
#define E 6
#define K 3
#define SH 32
#define HID 128
#define NKT 16    // K tiles of 64 (K = D = 1024)

typedef __attribute__((ext_vector_type(8))) short bf16x8;
typedef __attribute__((ext_vector_type(4))) float f32x4;

__device__ __forceinline__ unsigned short f2bf(float f) {
  unsigned u = __float_as_uint(f);
  return (unsigned short)((u + 0x7fffu + ((u >> 16) & 1u)) >> 16);
}

__device__ __forceinline__ void gload_lds16(const void* g, void* l) {
  __builtin_amdgcn_global_load_lds(
      (const __attribute__((address_space(1))) void*)g,
      (__attribute__((address_space(3))) void*)l, 16, 0, 0);
}

// ---------------- K0: per-expert inverse selection map (+ cnt zeroing) -------
__global__ void k_sel(const float* __restrict__ ml, int* __restrict__ inv,
                      int* __restrict__ cnt) {
  __shared__ float row[D];
  const int e = blockIdx.x, t = threadIdx.x;
  if (t == 0) cnt[e] = 0;
  row[t] = ml[e * D + t];
  __syncthreads();
  const float v = row[t];
  int rank = 0;
  for (int i = 0; i < D; ++i) {
    float u = row[i];
    rank += (u > v) || (u == v && i < t);
  }
  inv[e * D + t] = (rank < SEL) ? rank : -1;
}

// ---------------- K1a: WoWsp = Wo@Wsp (64x32) + bfull ----------------
__global__ __launch_bounds__(256) void k_wowsp(
    const float* __restrict__ Wo, const float* __restrict__ Wsp,
    const float* __restrict__ bo, const float* __restrict__ bsp,
    float* __restrict__ WoWsp, float* __restrict__ bfull) {
  __shared__ float red[256];
  const int t = threadIdx.x;
  const int j = t & 31, chunk = t >> 5;
  const int blk = blockIdx.x;
  float p = 0.f;
  if (blk < 64) {
    const int i = blk;
    for (int c = chunk * 64; c < chunk * 64 + 64; ++c)
      p += Wo[i * 512 + c] * Wsp[c * SH + j];
    red[t] = p;
    __syncthreads();
    if (t < 32) {
      float s = 0.f;
      #pragma unroll
      for (int k = 0; k < 8; ++k) s += red[k * 32 + j];
      WoWsp[i * SH + j] = s;
    }
  } else {
    for (int c = chunk * 64; c < chunk * 64 + 64; ++c)
      p += bo[c] * Wsp[c * SH + j];
    red[t] = p;
    __syncthreads();
    if (t < 32) {
      float s = bsp[j];
      #pragma unroll
      for (int k = 0; k < 8; ++k) s += red[k * 32 + j];
      bfull[j] = s;
    }
  }
}

// ---------------- K1b: Wfull = Wv @ WoWsp (512x32) ----------------
__global__ __launch_bounds__(256) void k_wfull2(
    const float* __restrict__ Wv, const float* __restrict__ WoWsp,
    float* __restrict__ Wfull) {
  __shared__ float wsh[64 * SH];
  const int t = threadIdx.x;
  for (int idx = t; idx < 64 * SH; idx += 256) wsh[idx] = WoWsp[idx];
  __syncthreads();
  const int c = blockIdx.x * 8 + (t >> 5), j = t & 31;
  float p = 0.f;
  #pragma unroll 8
  for (int i = 0; i < 64; ++i) p += Wv[c * 64 + i] * wsh[i * SH + j];
  Wfull[c * SH + j] = p;
}

// ---------------- K2: W1comb[e][h][d] bf16 (scatter + folded sinfo) ----------
__global__ __launch_bounds__(256) void k_w1c(
    const float* __restrict__ W1, const float* __restrict__ b1,
    const int* __restrict__ inv, const float* __restrict__ Wfull,
    const float* __restrict__ bfull,
    unsigned short* __restrict__ W1eT, float* __restrict__ b1c) {
  __shared__ float w1b[SH];
  __shared__ float bf[SH];
  const int e = blockIdx.x >> 7, h = blockIdx.x & 127;
  const int t = threadIdx.x;
  const float* We = W1 + (size_t)e * (SEL + SH) * HID;
  if (t < SH) { w1b[t] = We[(size_t)(SEL + t) * HID + h]; bf[t] = bfull[t]; }
  __syncthreads();
  const int* iv = inv + e * D;
  unsigned short* dst = W1eT + ((size_t)e * HID + h) * D;
  #pragma unroll
  for (int it = 0; it < 4; ++it) {
    int d = t + it * 256;
    int s = iv[d];
    float v = (s >= 0) ? We[(size_t)s * HID + h] : 0.f;
    if (d >= 512) {
      const float* wf = Wfull + (size_t)(d - 512) * SH;
      float p = 0.f;
      #pragma unroll
      for (int j = 0; j < SH; ++j) p += wf[j] * w1b[j];
      v += p;
    }
    dst[d] = f2bf(v);
  }
  if (t == 0) {
    float p = b1[e * HID + h];
    for (int j = 0; j < SH; ++j) p += bf[j] * w1b[j];
    b1c[e * HID + h] = p;
  }
}

// ---------------- K3: gate + xbf + top-3 compaction (fused) ----------------
// 512 blocks x 64 tokens. Wg in LDS [1024][8] (broadcast reads); x staged
// chunk-wise into xs[64][65] (2-way banks = free); lane owns a token, wave
// owns a d-quarter; LDS reduce; wave 0 does top-3 + softmax + ballot compact.
template<bool WRITE_XBF>
__global__ __launch_bounds__(256) void k_gate2(
    const float* __restrict__ x, const float* __restrict__ Wg,
    const float* __restrict__ bg, unsigned short* __restrict__ xbf,
    int* __restrict__ cnt, int* __restrict__ clist, float* __restrict__ wlist) {
  __shared__ float wgs[D * 8];        // 32 KB
  __shared__ float xs[64 * 65];       // 16.6 KB
  __shared__ float rbuf[3 * 64 * 6];  // 4.5 KB
  const int t = threadIdx.x;
  const int w = t >> 6, l = t & 63;
  const int tok0 = blockIdx.x * 64;

  for (int i = t; i < D * 6; i += 256) {
    int d = i / 6, e = i % 6;
    wgs[d * 8 + e] = Wg[i];
  }
  for (int d = t; d < D; d += 256) { wgs[d * 8 + 6] = 0.f; wgs[d * 8 + 7] = 0.f; }

  f32x4 accA = {0.f, 0.f, 0.f, 0.f};
  f32x4 accB = {0.f, 0.f, 0.f, 0.f};

  for (int c = 0; c < 16; ++c) {
    __syncthreads();
    #pragma unroll
    for (int q = 0; q < 4; ++q) {
      int fid = t + q * 256;
      int row = fid >> 4, col = fid & 15;
      float4 v = *(const float4*)(x + (size_t)(tok0 + row) * D + c * 64 + col * 4);
      if (WRITE_XBF) {
        ushort4 h4;
        h4.x = f2bf(v.x); h4.y = f2bf(v.y); h4.z = f2bf(v.z); h4.w = f2bf(v.w);
        *(ushort4*)(xbf + (size_t)(tok0 + row) * D + c * 64 + col * 4) = h4;
      }
      float* dst = &xs[row * 65 + col * 4];
      dst[0] = v.x; dst[1] = v.y; dst[2] = v.z; dst[3] = v.w;
    }
    __syncthreads();
    const int dbase = c * 64 + w * 16;
    #pragma unroll
    for (int dd = 0; dd < 16; ++dd) {
      const int dg = dbase + dd;
      f32x4 wa = *(const f32x4*)&wgs[dg * 8];
      f32x4 wb = *(const f32x4*)&wgs[dg * 8 + 4];
      float xv = xs[l * 65 + w * 16 + dd];
      accA += xv * wa;
      accB += xv * wb;
    }
  }

  if (w > 0) {
    float* rb = &rbuf[((w - 1) * 64 + l) * 6];
    rb[0] = accA[0]; rb[1] = accA[1]; rb[2] = accA[2]; rb[3] = accA[3];
    rb[4] = accB[0]; rb[5] = accB[1];
  }
  __syncthreads();
  if (w == 0) {
    float gv[E];
    gv[0] = accA[0]; gv[1] = accA[1]; gv[2] = accA[2];
    gv[3] = accA[3]; gv[4] = accB[0]; gv[5] = accB[1];
    #pragma unroll
    for (int p = 0; p < 3; ++p) {
      const float* rb = &rbuf[(p * 64 + l) * 6];
      #pragma unroll
      for (int e2 = 0; e2 < E; ++e2) gv[e2] += rb[e2];
    }
    #pragma unroll
    for (int e2 = 0; e2 < E; ++e2) gv[e2] += bg[e2];

    const int tok = tok0 + l;
    int idx[K]; float sc[K];
    bool used[E] = {};
    #pragma unroll
    for (int k = 0; k < K; ++k) {
      float best = -1e30f; int bi = 0;
      for (int e2 = 0; e2 < E; ++e2)
        if (!used[e2] && gv[e2] > best) { best = gv[e2]; bi = e2; }
      used[bi] = true; sc[k] = best; idx[k] = bi;
    }
    float s1 = __expf(sc[1] - sc[0]), s2 = __expf(sc[2] - sc[0]);
    float inv_s = 1.f / (1.f + s1 + s2);
    float tw[K] = {inv_s, s1 * inv_s, s2 * inv_s};
    const unsigned long long below = (1ULL << l) - 1ULL;
    #pragma unroll
    for (int e2 = 0; e2 < E; ++e2) {
      int myk = -1;
      #pragma unroll
      for (int k = 0; k < K; ++k) if (idx[k] == e2) myk = k;
      unsigned long long m = __ballot(myk >= 0);
      if (m) {
        int tot = __popcll(m);
        int leader = __ffsll((long long)m) - 1;
        int base = 0;
        if (l == leader) base = atomicAdd(&cnt[e2], tot);
        base = __shfl(base, leader);
        if (myk >= 0) {
          int pos = base + __popcll(m & below);
          clist[e2 * B + pos] = (tok << 2) | myk;
          wlist[e2 * B + pos] = tw[myk];
        }
      }
    }
  }
}

// ---------------- K5: compacted per-expert GEMM + relu·W2 epilogue ----------
template<int AMODE>
__global__ __launch_bounds__(256) void k_gemm(
    const float* __restrict__ x, const unsigned short* __restrict__ xbf,
    const unsigned short* __restrict__ W1eT,
    const int* __restrict__ cnt, const int* __restrict__ clist,
    const float* __restrict__ wlist,
    const float* __restrict__ b1c, const float* __restrict__ W2,
    const float* __restrict__ b2, float* __restrict__ eo4) {
  __shared__ __align__(16) char ldsA[128 * 128];
  __shared__ __align__(16) char ldsB[128 * 128];
  __shared__ int tokl[128];
  __shared__ float red[128];

  const int t = threadIdx.x;
  const int e = blockIdx.x >> 8;     // grid = E * 256
  const int bm = blockIdx.x & 255;
  const int n = cnt[e];
  if (bm * 128 >= n) return;
  const int cb = e * B;

  if (t < 128) {
    int gr = bm * 128 + t;
    tokl[t] = clist[cb + (gr < n ? gr : 0)] >> 2;
  }
  __syncthreads();

  const int w = t >> 6, lane = t & 63;
  const int g = lane >> 4, j = lane & 15;
  const int swz = ((lane & 7) * 16) ^ ((lane >> 3) << 4);

  const char* srcB[4];
  #pragma unroll
  for (int q = 0; q < 4; ++q)
    srcB[q] = (const char*)W1eT +
              (size_t)(e * HID + w * 32 + q * 8 + (lane >> 3)) * (D * 2) + swz;
  const char* srcA[4];
  if (AMODE == 0) {
    #pragma unroll
    for (int q = 0; q < 4; ++q)
      srcA[q] = (const char*)xbf +
                (size_t)tokl[w * 32 + q * 8 + (lane >> 3)] * 2048 + swz;
  }

  f32x4 acc[2][8] = {};

  for (int kt = 0; kt < NKT; ++kt) {
    if (kt) __syncthreads();
    if (AMODE == 0) {
      #pragma unroll
      for (int q = 0; q < 4; ++q)
        gload_lds16(srcA[q] + kt * 128, ldsA + w * 4096 + q * 1024);
    }
    #pragma unroll
    for (int q = 0; q < 4; ++q)
      gload_lds16(srcB[q] + kt * 128, ldsB + w * 4096 + q * 1024);
    if (AMODE == 1) {
      #pragma unroll
      for (int it = 0; it < 8; ++it) {
        int r = (t >> 4) + it * 16;
        const float4 v =
            *(const float4*)(x + (size_t)tokl[r] * D + kt * 64 + (t & 15) * 4);
        ushort4 h4;
        h4.x = f2bf(v.x); h4.y = f2bf(v.y); h4.z = f2bf(v.z); h4.w = f2bf(v.w);
        *(ushort4*)(ldsA + r * 128 + (((t & 15) * 8) ^ ((r & 7) << 4))) = h4;
      }
    }
    __syncthreads();
    #pragma unroll
    for (int kk = 0; kk < 2; ++kk) {
      const int kb = kk * 64 + g * 16;
      bf16x8 aF[2];
      #pragma unroll
      for (int fm = 0; fm < 2; ++fm) {
        int row = w * 32 + fm * 16 + j;
        aF[fm] = *(const bf16x8*)(ldsA + row * 128 + (kb ^ ((row & 7) << 4)));
      }
      #pragma unroll
      for (int fn = 0; fn < 8; ++fn) {
        int col = fn * 16 + j;
        bf16x8 bF = *(const bf16x8*)(ldsB + col * 128 + (kb ^ ((col & 7) << 4)));
        acc[0][fn] = __builtin_amdgcn_mfma_f32_16x16x32_bf16(aF[0], bF, acc[0][fn], 0, 0, 0);
        acc[1][fn] = __builtin_amdgcn_mfma_f32_16x16x32_bf16(aF[1], bF, acc[1][fn], 0, 0, 0);
      }
    }
  }

  float vb1[8], vw2[8];
  #pragma unroll
  for (int fn = 0; fn < 8; ++fn) {
    int col = fn * 16 + j;
    vb1[fn] = b1c[e * HID + col];
    vw2[fn] = W2[e * HID + col];
  }
  #pragma unroll
  for (int fm = 0; fm < 2; ++fm) {
    #pragma unroll
    for (int r = 0; r < 4; ++r) {
      float s = 0.f;
      #pragma unroll
      for (int fn = 0; fn < 8; ++fn)
        s += fmaxf(acc[fm][fn][r] + vb1[fn], 0.f) * vw2[fn];
      s += __shfl_xor(s, 1); s += __shfl_xor(s, 2);
      s += __shfl_xor(s, 4); s += __shfl_xor(s, 8);
      if (j == 0) red[w * 32 + fm * 16 + g * 4 + r] = s;
    }
  }
  __syncthreads();
  if (t < 128) {
    int gr = bm * 128 + t;
    if (gr < n) {
      int en = clist[cb + gr];
      eo4[(size_t)(en >> 2) * 4 + (en & 3)] = wlist[cb + gr] * (red[t] + b2[e]);
    }
  }
}

// ---------------- K6: sum the 3 weighted slots ----------------
__global__ void k_comb2(const float* __restrict__ eo4, float* __restrict__ out) {
  const int tok = blockIdx.x * 256 + threadIdx.x;
  float4 v = *(const float4*)(eo4 + (size_t)tok * 4);
  out[tok] = v.x + v.y + v.z;
}

extern "C" void kernel_launch(void* const* d_in, const int* in_sizes, int n_in,
                              void* d_out, int out_size, void* d_ws, size_t ws_size,
                              hipStream_t stream) {
  const float* x   = (const float*)d_in[0];
  const float* Wv  = (const float*)d_in[3];
  const float* Wo  = (const float*)d_in[4];
  const float* bo  = (const float*)d_in[5];
  const float* Wsp = (const float*)d_in[6];
  const float* bsp = (const float*)d_in[7];
  const float* Wg  = (const float*)d_in[8];
  const float* bg  = (const float*)d_in[9];
  const float* ml  = (const float*)d_in[10];
  const float* W1  = (const float*)d_in[11];
  const float* b1  = (const float*)d_in[12];
  const float* W2  = (const float*)d_in[13];
  const float* b2  = (const float*)d_in[14];
  float* out = (float*)d_out;

  char* ws = (char*)d_ws;
  int*   inv   = (int*)ws;                        // 24 KB
  float* WoWsp = (float*)(ws + 24576);            // 8 KB
  float* Wfull = (float*)(ws + 32768);            // 64 KB
  float* bfull = (float*)(ws + 98304);            // 128 B
  float* b1c   = (float*)(ws + 102400);           // 3 KB
  int*   cnt   = (int*)(ws + 106496);             // 32 B
  int*   clist = (int*)(ws + 925696);             // 768 KB
  float* wlist = (float*)(ws + 1712128);          // 768 KB
  float* eo4   = (float*)(ws + 2498560);          // 512 KB
  unsigned short* W1eT = (unsigned short*)(ws + 3022848);  // 1.5 MB
  unsigned short* xbf  = (unsigned short*)(ws + 4595712);  // 64 MB (optional)
  const bool use_xbf = ws_size >= (size_t)4595712 + (size_t)B * D * 2;

  k_sel<<<E, D, 0, stream>>>(ml, inv, cnt);
  k_wowsp<<<65, 256, 0, stream>>>(Wo, Wsp, bo, bsp, WoWsp, bfull);
  k_wfull2<<<64, 256, 0, stream>>>(Wv, WoWsp, Wfull);
  k_w1c<<<E * HID, 256, 0, stream>>>(W1, b1, inv, Wfull, bfull, W1eT, b1c);
  if (use_xbf)
    k_gate2<true><<<B / 64, 256, 0, stream>>>(x, Wg, bg, xbf, cnt, clist, wlist);
  else
    k_gate2<false><<<B / 64, 256, 0, stream>>>(x, Wg, bg, xbf, cnt, clist, wlist);
  if (use_xbf)
    k_gemm<0><<<E * 256, 256, 0, stream>>>(x, xbf, W1eT, cnt, clist, wlist, b1c, W2, b2, eo4);
  else
    k_gemm<1><<<E * 256, 256, 0, stream>>>(x, xbf, W1eT, cnt, clist, wlist, b1c, W2, b2, eo4);
  k_comb2<<<B / 256, 256, 0, stream>>>(eo4, out);
}